// Round 15
// baseline (1053.051 us; speedup 1.0000x reference)
//
#include <hip/hip_runtime.h>
#include <math.h>

typedef unsigned short u16;
typedef __attribute__((ext_vector_type(8))) short short8;
typedef __attribute__((ext_vector_type(4))) float f32x4;
typedef __attribute__((ext_vector_type(4))) unsigned short u16x4;

// Problem dims
constexpr int  Bn   = 512;
constexpr int  Cch  = 64;
constexpr int  Dd   = 512;
constexpr int  DV3  = 192;
constexpr long BCD  = (long)Bn * Cch * Dd;
constexpr int  MTOT = Bn * Cch;                // 32768
constexpr long NZv  = (long)Bn * Cch * DV3;

__device__ __forceinline__ float eluf(float v) { return v > 0.f ? v : expm1f(v); }

__device__ __forceinline__ u16 f2bf(float f) {
  unsigned u = __float_as_uint(f);
  unsigned r = u + 0x7fffu + ((u >> 16) & 1u);
  return (u16)(r >> 16);
}
__device__ __forceinline__ float bf2f(u16 h) { return __uint_as_float(((unsigned)h) << 16); }

typedef __attribute__((address_space(1))) const unsigned int gu32;
typedef __attribute__((address_space(3))) unsigned int lu32;
__device__ __forceinline__ void g2l16(const void* g, void* l) {
  __builtin_amdgcn_global_load_lds((gu32*)g, (lu32*)l, 16, 0, 0);
}

// ---------------- dynamic graph (parallel, 3 stages) ----------------
__global__ __launch_bounds__(256) void k_dg1(
    const float* __restrict__ A_init, const float* __restrict__ f1w,
    float* __restrict__ pmid)
{
  int kb = blockIdx.x, z = blockIdx.y, t = threadIdx.x;
  __shared__ float sA[128];
  if (t < 128) sA[t] = A_init[kb * 128 + t];
  __syncthreads();
  const float* w1 = f1w + (long)z * 4096 * 256 + (long)kb * 128 * 256;
  float acc = 0.f;
  #pragma unroll 8
  for (int k = 0; k < 128; ++k) acc = fmaf(sA[k], w1[(long)k * 256 + t], acc);
  pmid[(z * 32 + kb) * 256 + t] = acc;
}

__global__ __launch_bounds__(256) void k_dg2(
    const float* __restrict__ pmid, const float* __restrict__ f1b,
    float* __restrict__ mid)
{
  int z = blockIdx.x, t = threadIdx.x;
  float s = f1b[z * 256 + t];
  #pragma unroll
  for (int kb = 0; kb < 32; ++kb) s += pmid[(z * 32 + kb) * 256 + t];
  mid[z * 256 + t] = eluf(s);
}

__global__ __launch_bounds__(256) void k_dg3(
    const float* __restrict__ mid, const float* __restrict__ f2w,
    const float* __restrict__ f2b,
    float* __restrict__ A_dyn, float* __restrict__ A_norm)
{
  int jb = blockIdx.x, z = blockIdx.y, t = threadIdx.x;
  __shared__ float sM[256];
  sM[t] = mid[z * 256 + t];
  __syncthreads();
  int j = jb * 256 + t;
  const float* w2 = f2w + (long)z * 256 * 4096;
  float acc = f2b[z * 4096 + j];
  #pragma unroll 8
  for (int k = 0; k < 256; ++k) acc = fmaf(sM[k], w2[(long)k * 4096 + j], acc);
  float a = fmaxf(acc, 0.f);
  A_dyn[z * 4096 + j] = a;
  float s = a;
  s += __shfl_xor(s, 1);  s += __shfl_xor(s, 2);  s += __shfl_xor(s, 4);
  s += __shfl_xor(s, 8);  s += __shfl_xor(s, 16); s += __shfl_xor(s, 32);
  A_norm[z * 4096 + j] = a / (s + 1e-6f);
}

// ---------------- weight transpose: (z,K,N) f32 -> (z,Npad,K) bf16 (hi only) ----------------
__global__ __launch_bounds__(256) void k_cvt_wTh(
    const float* __restrict__ w, u16* __restrict__ hT, int K, int N, int Npad)
{
  int k0 = blockIdx.x * 32, n0 = blockIdx.y * 32, z = blockIdx.z;
  int t = threadIdx.x;
  int tr = t >> 3, tc = (t & 7) * 4;
  long o = (long)z * Npad * K + (long)(n0 + tr) * K + k0 + tc;
  if (n0 >= N) {
    u16x4 zz = {0, 0, 0, 0};
    *(u16x4*)&hT[o] = zz;
    return;
  }
  __shared__ float sT[32][33];
  float4 v = *(const float4*)&w[(long)z * K * N + (long)(k0 + tr) * N + n0 + tc];
  sT[tr][tc + 0] = v.x; sT[tr][tc + 1] = v.y;
  sT[tr][tc + 2] = v.z; sT[tr][tc + 3] = v.w;
  __syncthreads();
  u16x4 h;
  h.x = f2bf(sT[tc + 0][tr]); h.y = f2bf(sT[tc + 1][tr]);
  h.z = f2bf(sT[tc + 2][tr]); h.w = f2bf(sT[tc + 3][tr]);
  *(u16x4*)&hT[o] = h;
}

// concat wq|wk|wv -> (z,256,512) transposed bf16, rows 192..255 zero
__global__ __launch_bounds__(256) void k_cvt_qkvTh(
    const float* __restrict__ wq, const float* __restrict__ wk, const float* __restrict__ wv,
    u16* __restrict__ hT)
{
  int k0 = blockIdx.x * 32, n0 = blockIdx.y * 32, z = blockIdx.z;
  int t = threadIdx.x;
  int tr = t >> 3, tc = (t & 7) * 4;
  long o = (long)z * 256 * 512 + (long)(n0 + tr) * 512 + k0 + tc;
  if (n0 >= 192) {
    u16x4 zz = {0, 0, 0, 0};
    *(u16x4*)&hT[o] = zz;
    return;
  }
  const float* src = (n0 < 64) ? wq : (n0 < 128) ? wk : wv;
  int nsub = n0 & 63;
  __shared__ float sT[32][33];
  float4 v = *(const float4*)&src[(long)z * 512 * 64 + (long)(k0 + tr) * 64 + nsub + tc];
  sT[tr][tc + 0] = v.x; sT[tr][tc + 1] = v.y;
  sT[tr][tc + 2] = v.z; sT[tr][tc + 3] = v.w;
  __syncthreads();
  u16x4 h;
  h.x = f2bf(sT[tc + 0][tr]); h.y = f2bf(sT[tc + 1][tr]);
  h.z = f2bf(sT[tc + 2][tr]); h.w = f2bf(sT[tc + 3][tr]);
  *(u16x4*)&hT[o] = h;
}

__global__ __launch_bounds__(256) void k_cvt_qkvb(
    const float* __restrict__ bq, const float* __restrict__ bk, const float* __restrict__ bv,
    float* __restrict__ bcat)
{
  int idx = blockIdx.x * 256 + threadIdx.x;
  if (idx >= 768) return;
  int z = idx >> 8, n = idx & 255;
  float v = 0.f;
  if (n < 64)       v = bq[z * 64 + n];
  else if (n < 128) v = bk[z * 64 + (n - 64)];
  else if (n < 192) v = bv[z * 64 + (n - 128)];
  bcat[idx] = v;
}

// pack 4 bias vectors (192 each) into contiguous buffer
__global__ __launch_bounds__(256) void k_pack4(
    const float* __restrict__ b0, const float* __restrict__ b1,
    const float* __restrict__ b2, const float* __restrict__ b3,
    float* __restrict__ dst)
{
  int idx = blockIdx.x * 256 + threadIdx.x;   // 768 total
  if (idx >= 768) return;
  int z = idx / 192, n = idx % 192;
  const float* s = (z == 0) ? b0 : (z == 1) ? b1 : (z == 2) ? b2 : b3;
  dst[idx] = s[n];
}

// ---------------- split GEMM, fat steps + counted vmcnt + setprio ----------------
// Tile 128x128, BK=32, 4 waves, multi-buffered LDS, counted vmcnt (never 0 in
// main loop), raw s_barrier, setprio around MFMA.
// AMODE: 0 = A bf16 hi/lo (2-pass, depth-2), 1 = A f32 (2-pass, in-reg extract,
//        depth-2), 2 = A bf16 single (1-pass, depth-3 pipeline).
// OMODE: 0 = f32 out, 1 = bf16 hi/lo out, 2 = bf16 hi-only out.
// ACT: 0 none, 1 relu, 2 elu, 3 per-z (z0 relu, z1 elu).
// Dead-wave skip: waves whose 64-col slab is entirely >= Nout (N-padding) skip
// ds_reads + MFMA (exact-math; they still stage and hit barriers).
template<int ACT, int OMODE, int AMODE, bool RES>
__global__ __launch_bounds__(256) void k_mgemm(
    int N, int K, int lda, int ldo, int Nout,
    const u16* __restrict__ Ah, const u16* __restrict__ Al, long a_zs,
    const u16* __restrict__ Bh, long b_zs,
    const float* __restrict__ bias, long bias_zs,
    float* __restrict__ outF, u16* __restrict__ outH, u16* __restrict__ outL, long o_zs,
    const float* __restrict__ resid)
{
  // XCD-aware swizzle (all grids here have nwg % 8 == 0)
  int gx = gridDim.x, gy = gridDim.y;
  int nwg = gx * gy * (int)gridDim.z;
  int bid = (int)blockIdx.x + gx * ((int)blockIdx.y + gy * (int)blockIdx.z);
  int L = ((nwg & 7) == 0) ? ((bid & 7) * (nwg >> 3) + (bid >> 3)) : bid;
  int n0 = (L % gx) * 128;
  int m0 = ((L / gx) % gy) * 128;
  int z  = L / (gx * gy);

  const u16* ah = Ah + z * a_zs;
  const u16* al = (AMODE == 0) ? (Al + z * a_zs) : (const u16*)nullptr;
  const u16* bh = Bh + z * b_zs;

  constexpr int LDSU = (AMODE == 2) ? 8192 : 12288;
  constexpr int BOFF = (AMODE == 2) ? 4096 : 8192;
  constexpr int NBUF = (AMODE == 2) ? 3 : 2;
  __shared__ u16 sm[NBUF][LDSU];

  int t = threadIdx.x, wv = t >> 6, ln = t & 63;
  int mh = wv >> 1, nh = wv & 1;
  int lr = ln & 15, lk8 = (ln >> 4) * 8;
  int colb = n0 + nh * 64;
  bool live = (colb < Nout);     // wave-uniform; false only for N-padding slabs
  f32x4 acc[4][4] = {};

  auto stage = [&](int pp, int kt) {
    u16* smp = sm[pp];
    if (AMODE == 2) {
      #pragma unroll
      for (int s = 0; s < 4; ++s) {
        int c = s * 4 + wv;                  // 0..15
        if (c < 8) {
          const u16* g = ah + (long)(m0 + c * 16 + lr) * lda + kt + lk8;
          g2l16(g, smp + c * 512 + ln * 8);
        } else {
          int tile = c - 8;
          const u16* g = bh + (long)(n0 + tile * 16 + lr) * K + kt + lk8;
          g2l16(g, smp + 4096 + tile * 512 + ln * 8);
        }
      }
    } else {
      #pragma unroll
      for (int s = 0; s < 2; ++s) {
        int tile = s * 4 + wv;               // 0..7
        long rowA = (long)(m0 + tile * 16 + lr);
        if (AMODE == 1) {
          const float* Af = reinterpret_cast<const float*>(ah);
          const float* g = Af + rowA * lda + kt + lk8;
          g2l16(g,     smp + tile * 1024 + ln * 8);
          g2l16(g + 4, smp + tile * 1024 + 512 + ln * 8);
        } else {
          const u16* gA  = ah + rowA * lda + kt + lk8;
          const u16* gAl = al + rowA * lda + kt + lk8;
          g2l16(gA,  smp + tile * 512 + ln * 8);
          g2l16(gAl, smp + 4096 + tile * 512 + ln * 8);
        }
        const u16* gB = bh + (long)(n0 + tile * 16 + lr) * K + kt + lk8;
        g2l16(gB, smp + 8192 + tile * 512 + ln * 8);
      }
    }
  };

  int nsteps = K >> 5;                       // >= 6 for all call sites
  stage(0, 0);
  stage(1, 32);
  if (NBUF == 3) stage(2, 64);

  for (int it = 0; it < nsteps; ++it) {
    int b = (NBUF == 3) ? (it % 3) : (it & 1);
    if (NBUF == 3) {
      if (it + 2 < nsteps)      { asm volatile("s_waitcnt vmcnt(8)" ::: "memory"); }
      else if (it + 1 < nsteps) { asm volatile("s_waitcnt vmcnt(4)" ::: "memory"); }
      else                      { asm volatile("s_waitcnt vmcnt(0)" ::: "memory"); }
    } else {
      if (it + 1 < nsteps) { asm volatile("s_waitcnt vmcnt(6)" ::: "memory"); }
      else                 { asm volatile("s_waitcnt vmcnt(0)" ::: "memory"); }
    }
    __builtin_amdgcn_sched_barrier(0);
    __builtin_amdgcn_s_barrier();

    short8 a_h[4], a_l[4], b_h[4];
    if (live) {
      if (AMODE == 1) {
        const float* fp = reinterpret_cast<const float*>(sm[b]);
        #pragma unroll
        for (int f = 0; f < 4; ++f) {
          f32x4 lo = *(const f32x4*)&fp[(mh * 4 + f) * 512 + ln * 4];
          f32x4 hi = *(const f32x4*)&fp[(mh * 4 + f) * 512 + 256 + ln * 4];
          #pragma unroll
          for (int e = 0; e < 4; ++e) {
            unsigned ul = __float_as_uint(lo[e]), uh = __float_as_uint(hi[e]);
            a_h[f][e]     = (short)(ul >> 16);
            a_h[f][e + 4] = (short)(uh >> 16);
            float rl = lo[e] - __uint_as_float(ul & 0xffff0000u);
            float rh = hi[e] - __uint_as_float(uh & 0xffff0000u);
            a_l[f][e]     = (short)(__float_as_uint(rl) >> 16);
            a_l[f][e + 4] = (short)(__float_as_uint(rh) >> 16);
          }
        }
      } else {
        #pragma unroll
        for (int f = 0; f < 4; ++f) {
          a_h[f] = *(const short8*)&sm[b][(mh * 4 + f) * 512 + ln * 8];
          if (AMODE == 0)
            a_l[f] = *(const short8*)&sm[b][4096 + (mh * 4 + f) * 512 + ln * 8];
        }
      }
      #pragma unroll
      for (int f = 0; f < 4; ++f)
        b_h[f] = *(const short8*)&sm[b][BOFF + (nh * 4 + f) * 512 + ln * 8];
    }

    asm volatile("s_waitcnt lgkmcnt(0)" ::: "memory");
    __builtin_amdgcn_sched_barrier(0);
    __builtin_amdgcn_s_barrier();          // all reads of buf b done

    if (it + NBUF < nsteps) stage(b, (it + NBUF) << 5);

    if (live) {
      __builtin_amdgcn_s_setprio(1);
      #pragma unroll
      for (int i = 0; i < 4; ++i)
        #pragma unroll
        for (int j = 0; j < 4; ++j) {
          acc[i][j] = __builtin_amdgcn_mfma_f32_16x16x32_bf16(a_h[i], b_h[j], acc[i][j], 0, 0, 0);
          if (AMODE != 2)
            acc[i][j] = __builtin_amdgcn_mfma_f32_16x16x32_bf16(a_l[i], b_h[j], acc[i][j], 0, 0, 0);
        }
      __builtin_amdgcn_s_setprio(0);
    }
  }

  int rowb = m0 + mh * 64;
  if (live) {
    #pragma unroll
    for (int i = 0; i < 4; ++i) {
      #pragma unroll
      for (int j = 0; j < 4; ++j) {
        int col = colb + j * 16 + lr;
        if (col < Nout) {
          float bv = bias[z * bias_zs + col];
          #pragma unroll
          for (int r = 0; r < 4; ++r) {
            long row = rowb + i * 16 + (ln >> 4) * 4 + r;
            float v = acc[i][j][r] + bv;
            if (ACT == 1) v = fmaxf(v, 0.f);
            if (ACT == 2) v = eluf(v);
            if (ACT == 3) v = (z == 0) ? fmaxf(v, 0.f) : eluf(v);
            if (RES) v += resid[z * o_zs + row * ldo + col];
            if (OMODE == 0) {
              outF[z * o_zs + row * ldo + col] = v;
            } else if (OMODE == 1) {
              u16 h = f2bf(v);
              outH[z * o_zs + row * ldo + col] = h;
              outL[z * o_zs + row * ldo + col] = f2bf(v - bf2f(h));
            } else {
              outH[z * o_zs + row * ldo + col] = f2bf(v);
            }
          }
        }
      }
    }
  }
}

// ---------------- diffusion: G = elu(A_norm @ h + x) -> bf16 hi/lo ----------------
__global__ __launch_bounds__(256) void k_diffuse(
    const float* __restrict__ A_norm, const u16* __restrict__ Hh,
    const float* __restrict__ x,
    u16* __restrict__ Gh, u16* __restrict__ Gl, int b0, int NB)
{
  int b = blockIdx.x, br = blockIdx.y, t = threadIdx.x;
  __shared__ float sAT[64 * 64];
  __shared__ float sH[64 * 64];
  const float* An = A_norm + br * 4096;
  for (int idx = t; idx < 4096; idx += 256)
    sAT[(idx & 63) * 64 + (idx >> 6)] = An[idx];
  const u16* hhb = Hh + ((long)br * NB + b) * (64 * 512);
  const float* xb = x + ((long)br * Bn + (b0 + b)) * (64 * 512);
  u16* Ghb = Gh + ((long)br * NB + b) * (64 * 512);
  u16* Glb = Gl + ((long)br * NB + b) * (64 * 512);
  int c4 = t & 15, rb = (t >> 4) * 4;
  for (int dc = 0; dc < 512; dc += 64) {
    __syncthreads();
    for (int idx = t * 4; idx < 4096; idx += 1024) {
      int r = idx >> 6, c = idx & 63;
      u16x4 ha = *(const u16x4*)&hhb[(long)r * 512 + dc + c];
      sH[idx + 0] = bf2f(ha.x);
      sH[idx + 1] = bf2f(ha.y);
      sH[idx + 2] = bf2f(ha.z);
      sH[idx + 3] = bf2f(ha.w);
    }
    __syncthreads();
    float acc[4][4] = {};
    #pragma unroll 4
    for (int j = 0; j < 64; ++j) {
      float a0 = sAT[j * 64 + rb + 0], a1 = sAT[j * 64 + rb + 1];
      float a2 = sAT[j * 64 + rb + 2], a3 = sAT[j * 64 + rb + 3];
      float4 hv = *(const float4*)&sH[j * 64 + c4 * 4];
      acc[0][0] = fmaf(a0, hv.x, acc[0][0]); acc[0][1] = fmaf(a0, hv.y, acc[0][1]);
      acc[0][2] = fmaf(a0, hv.z, acc[0][2]); acc[0][3] = fmaf(a0, hv.w, acc[0][3]);
      acc[1][0] = fmaf(a1, hv.x, acc[1][0]); acc[1][1] = fmaf(a1, hv.y, acc[1][1]);
      acc[1][2] = fmaf(a1, hv.z, acc[1][2]); acc[1][3] = fmaf(a1, hv.w, acc[1][3]);
      acc[2][0] = fmaf(a2, hv.x, acc[2][0]); acc[2][1] = fmaf(a2, hv.y, acc[2][1]);
      acc[2][2] = fmaf(a2, hv.z, acc[2][2]); acc[2][3] = fmaf(a2, hv.w, acc[2][3]);
      acc[3][0] = fmaf(a3, hv.x, acc[3][0]); acc[3][1] = fmaf(a3, hv.y, acc[3][1]);
      acc[3][2] = fmaf(a3, hv.z, acc[3][2]); acc[3][3] = fmaf(a3, hv.w, acc[3][3]);
    }
    #pragma unroll
    for (int i = 0; i < 4; ++i) {
      float4 xv = *(const float4*)&xb[(long)(rb + i) * 512 + dc + c4 * 4];
      float v0 = eluf(acc[i][0] + xv.x);
      float v1 = eluf(acc[i][1] + xv.y);
      float v2 = eluf(acc[i][2] + xv.z);
      float v3 = eluf(acc[i][3] + xv.w);
      u16x4 hh, ll;
      hh.x = f2bf(v0); ll.x = f2bf(v0 - bf2f(hh.x));
      hh.y = f2bf(v1); ll.y = f2bf(v1 - bf2f(hh.y));
      hh.z = f2bf(v2); ll.z = f2bf(v2 - bf2f(hh.z));
      hh.w = f2bf(v3); ll.w = f2bf(v3 - bf2f(hh.w));
      long o = (long)(rb + i) * 512 + dc + c4 * 4;
      *(u16x4*)&Ghb[o] = hh;
      *(u16x4*)&Glb[o] = ll;
    }
  }
}

// ---------------- attention + A_dyn apply (qkv in bf16) ----------------
__global__ __launch_bounds__(256) void k_attn(
    const u16* __restrict__ qkv, const float* __restrict__ A_dyn,
    float* __restrict__ Zl, int b0, int NB)
{
  int b = blockIdx.x, br = blockIdx.y, t = threadIdx.x;
  __shared__ float sQ[64 * 65];
  __shared__ float sK[64 * 65];
  __shared__ float sS[64 * 65];
  const u16* Qb = qkv + ((long)br * NB + b) * (64 * 256);
  for (int idx = t * 4; idx < 4096; idx += 1024) {
    int r = idx >> 6, c = idx & 63;
    u16x4 q4 = *(const u16x4*)&Qb[(long)r * 256 + c];
    u16x4 k4 = *(const u16x4*)&Qb[(long)r * 256 + 64 + c];
    sQ[r * 65 + c + 0] = bf2f(q4.x); sQ[r * 65 + c + 1] = bf2f(q4.y);
    sQ[r * 65 + c + 2] = bf2f(q4.z); sQ[r * 65 + c + 3] = bf2f(q4.w);
    sK[r * 65 + c + 0] = bf2f(k4.x); sK[r * 65 + c + 1] = bf2f(k4.y);
    sK[r * 65 + c + 2] = bf2f(k4.z); sK[r * 65 + c + 3] = bf2f(k4.w);
  }
  __syncthreads();
  int c4 = t & 15, rb = (t >> 4) * 4;
  float acc[4][4] = {};
  #pragma unroll 4
  for (int k = 0; k < 64; ++k) {
    float a0 = sQ[(rb + 0) * 65 + k], a1 = sQ[(rb + 1) * 65 + k];
    float a2 = sQ[(rb + 2) * 65 + k], a3 = sQ[(rb + 3) * 65 + k];
    #pragma unroll
    for (int q = 0; q < 4; ++q) {
      float bq = sK[(c4 * 4 + q) * 65 + k];
      acc[0][q] = fmaf(a0, bq, acc[0][q]); acc[1][q] = fmaf(a1, bq, acc[1][q]);
      acc[2][q] = fmaf(a2, bq, acc[2][q]); acc[3][q] = fmaf(a3, bq, acc[3][q]);
    }
  }
  #pragma unroll
  for (int i = 0; i < 4; ++i)
    #pragma unroll
    for (int q = 0; q < 4; ++q)
      sS[(rb + i) * 65 + c4 * 4 + q] = acc[i][q] * 0.125f;
  __syncthreads();
  {
    int r = t >> 2, l = t & 3;
    float m = -3.4e38f;
    #pragma unroll
    for (int c = 0; c < 16; ++c) m = fmaxf(m, sS[r * 65 + l * 16 + c]);
    m = fmaxf(m, __shfl_xor(m, 1));
    m = fmaxf(m, __shfl_xor(m, 2));
    float s = 0.f, e[16];
    #pragma unroll
    for (int c = 0; c < 16; ++c) { e[c] = expf(sS[r * 65 + l * 16 + c] - m); s += e[c]; }
    s += __shfl_xor(s, 1);
    s += __shfl_xor(s, 2);
    float inv = 1.f / s;
    #pragma unroll
    for (int c = 0; c < 16; ++c) sS[r * 65 + l * 16 + c] = e[c] * inv;
  }
  __syncthreads();
  for (int idx = t * 4; idx < 4096; idx += 1024) {
    int r = idx >> 6, c = idx & 63;
    u16x4 v4 = *(const u16x4*)&Qb[(long)r * 256 + 128 + c];
    sQ[r * 65 + c + 0] = bf2f(v4.x); sQ[r * 65 + c + 1] = bf2f(v4.y);
    sQ[r * 65 + c + 2] = bf2f(v4.z); sQ[r * 65 + c + 3] = bf2f(v4.w);
  }
  __syncthreads();
  float pv[4][4] = {};
  #pragma unroll 4
  for (int j = 0; j < 64; ++j) {
    float p0 = sS[(rb + 0) * 65 + j], p1 = sS[(rb + 1) * 65 + j];
    float p2 = sS[(rb + 2) * 65 + j], p3 = sS[(rb + 3) * 65 + j];
    #pragma unroll
    for (int q = 0; q < 4; ++q) {
      float vq = sQ[j * 65 + c4 * 4 + q];
      pv[0][q] = fmaf(p0, vq, pv[0][q]); pv[1][q] = fmaf(p1, vq, pv[1][q]);
      pv[2][q] = fmaf(p2, vq, pv[2][q]); pv[3][q] = fmaf(p3, vq, pv[3][q]);
    }
  }
  #pragma unroll
  for (int i = 0; i < 4; ++i)
    #pragma unroll
    for (int q = 0; q < 4; ++q)
      sK[(rb + i) * 65 + c4 * 4 + q] = pv[i][q];
  __syncthreads();
  const float* Ad = A_dyn + br * 4096;
  for (int idx = t; idx < 4096; idx += 256)
    sS[(idx >> 6) * 65 + (idx & 63)] = Ad[idx];
  __syncthreads();
  float zz[4][4] = {};
  #pragma unroll 4
  for (int j = 0; j < 64; ++j) {
    float a0 = sS[(rb + 0) * 65 + j], a1 = sS[(rb + 1) * 65 + j];
    float a2 = sS[(rb + 2) * 65 + j], a3 = sS[(rb + 3) * 65 + j];
    #pragma unroll
    for (int q = 0; q < 4; ++q) {
      float p = sK[j * 65 + c4 * 4 + q];
      zz[0][q] = fmaf(a0, p, zz[0][q]); zz[1][q] = fmaf(a1, p, zz[1][q]);
      zz[2][q] = fmaf(a2, p, zz[2][q]); zz[3][q] = fmaf(a3, p, zz[3][q]);
    }
  }
  long zbase = ((long)(b0 + b) * 64) * 192 + br * 64;
  #pragma unroll
  for (int i = 0; i < 4; ++i) {
    float4 o; o.x = zz[i][0]; o.y = zz[i][1]; o.z = zz[i][2]; o.w = zz[i][3];
    *(float4*)&Zl[zbase + (long)(rb + i) * 192 + c4 * 4] = o;
  }
}

// ---------------- f32 GEMM (output head only, split-K) ----------------
template<int ACT, bool RES, bool SPLITK>
__global__ __launch_bounds__(256) void k_gemm(
    int M, int N, int K,
    const float* __restrict__ A, long a_zs, int lda,
    const float* __restrict__ W, long w_zs,
    const float* __restrict__ bias, long b_zs,
    float* __restrict__ out, long o_zs,
    const float* __restrict__ resid, int k_chunk)
{
  int z  = blockIdx.z;
  int n0 = blockIdx.x * 64, m0 = blockIdx.y * 64;
  const float* Ab = A + (SPLITK ? 0 : z * a_zs);
  const float* Wb = W + (SPLITK ? 0 : z * w_zs);
  float* ob = out + z * o_zs;
  const float* bb = bias ? bias + z * b_zs : nullptr;
  const float* rb_ = RES ? resid + z * o_zs : nullptr;
  int k0   = SPLITK ? z * k_chunk : 0;
  int kend = SPLITK ? k0 + k_chunk : K;

  __shared__ float As[16][68];
  __shared__ float Bs[16][68];
  float acc[4][4] = {};
  int t  = threadIdx.x;
  int tm = t & 15, tn = t >> 4;
  int ar = t >> 2, ak = (t & 3) * 4;
  int bk = t >> 4, bn = (t & 15) * 4;

  for (int kt = k0; kt < kend; kt += 16) {
    float4 av = *(const float4*)&Ab[(long)(m0 + ar) * lda + kt + ak];
    float4 bv = *(const float4*)&Wb[(long)(kt + bk) * N + n0 + bn];
    __syncthreads();
    As[ak + 0][ar] = av.x; As[ak + 1][ar] = av.y;
    As[ak + 2][ar] = av.z; As[ak + 3][ar] = av.w;
    *(float4*)&Bs[bk][bn] = bv;
    __syncthreads();
    #pragma unroll
    for (int k = 0; k < 16; ++k) {
      float4 a = *(const float4*)&As[k][tm * 4];
      float4 b = *(const float4*)&Bs[k][tn * 4];
      acc[0][0] = fmaf(a.x, b.x, acc[0][0]); acc[0][1] = fmaf(a.x, b.y, acc[0][1]);
      acc[0][2] = fmaf(a.x, b.z, acc[0][2]); acc[0][3] = fmaf(a.x, b.w, acc[0][3]);
      acc[1][0] = fmaf(a.y, b.x, acc[1][0]); acc[1][1] = fmaf(a.y, b.y, acc[1][1]);
      acc[1][2] = fmaf(a.y, b.z, acc[1][2]); acc[1][3] = fmaf(a.y, b.w, acc[1][3]);
      acc[2][0] = fmaf(a.z, b.x, acc[2][0]); acc[2][1] = fmaf(a.z, b.y, acc[2][1]);
      acc[2][2] = fmaf(a.z, b.z, acc[2][2]); acc[2][3] = fmaf(a.z, b.w, acc[2][3]);
      acc[3][0] = fmaf(a.w, b.x, acc[3][0]); acc[3][1] = fmaf(a.w, b.y, acc[3][1]);
      acc[3][2] = fmaf(a.w, b.z, acc[3][2]); acc[3][3] = fmaf(a.w, b.w, acc[3][3]);
    }
  }

  #pragma unroll
  for (int i = 0; i < 4; ++i) {
    long row = m0 + tm * 4 + i;
    int  col = n0 + tn * 4;
    float v[4];
    #pragma unroll
    for (int j = 0; j < 4; ++j) {
      float x = acc[i][j] + (bb ? bb[col + j] : 0.f);
      if (ACT == 1) x = fmaxf(x, 0.f);
      if (ACT == 2) x = eluf(x);
      v[j] = x;
    }
    if (RES) {
      float4 r = *(const float4*)&rb_[row * N + col];
      v[0] += r.x; v[1] += r.y; v[2] += r.z; v[3] += r.w;
    }
    float4 o; o.x = v[0]; o.y = v[1]; o.z = v[2]; o.w = v[3];
    *(float4*)&ob[row * N + col] = o;
  }
}

// ---------------- fusion: cw softmax + Zg = (A_init @ Zl) * cw; Zln = LN(Zg) ----------------
__global__ __launch_bounds__(256) void k_fuse2(
    const float* __restrict__ Zl, const float* __restrict__ A_init,
    const float* __restrict__ ln_g, const float* __restrict__ ln_b,
    u16* __restrict__ ZgH, u16* __restrict__ ZgL,
    u16* __restrict__ ZlnH, u16* __restrict__ ZlnL)
{
  int b = blockIdx.x, t = threadIdx.x;
  __shared__ float sAT[64 * 64];
  __shared__ float sH[64 * 68];
  __shared__ float sCW[192];
  const float* Zb = Zl + (long)b * 12288;
  if (t < 192) {
    float s = 0.f;
    #pragma unroll 8
    for (int j = 0; j < 64; ++j) s += Zb[j * 192 + t];
    sCW[t] = s * (1.f / 64.f);
  }
  for (int idx = t; idx < 4096; idx += 256)
    sAT[(idx & 63) * 64 + (idx >> 6)] = A_init[idx];
  __syncthreads();
  float m = -3.4e38f;
  for (int d = 0; d < 192; ++d) m = fmaxf(m, sCW[d]);
  float ssum = 0.f;
  for (int d = 0; d < 192; ++d) ssum += expf(sCW[d] - m);
  float cinv = 1.f / ssum;

  long obase = (long)b * 12288;
  int c4 = t & 15, rb = (t >> 4) * 4;
  float zg[3][4][4];
  float rs[4] = {0.f, 0.f, 0.f, 0.f};
  float rs2[4] = {0.f, 0.f, 0.f, 0.f};

  #pragma unroll
  for (int cc = 0; cc < 3; ++cc) {
    __syncthreads();
    for (int idx = t * 4; idx < 4096; idx += 1024) {
      int r = idx >> 6, c = idx & 63;
      float4 v = *(const float4*)&Zb[(long)r * 192 + cc * 64 + c];
      *(float4*)&sH[r * 68 + c] = v;
    }
    __syncthreads();
    float acc[4][4] = {};
    #pragma unroll 4
    for (int j = 0; j < 64; ++j) {
      float a0 = sAT[j * 64 + rb + 0], a1 = sAT[j * 64 + rb + 1];
      float a2 = sAT[j * 64 + rb + 2], a3 = sAT[j * 64 + rb + 3];
      float4 hv = *(const float4*)&sH[j * 68 + c4 * 4];
      acc[0][0] = fmaf(a0, hv.x, acc[0][0]); acc[0][1] = fmaf(a0, hv.y, acc[0][1]);
      acc[0][2] = fmaf(a0, hv.z, acc[0][2]); acc[0][3] = fmaf(a0, hv.w, acc[0][3]);
      acc[1][0] = fmaf(a1, hv.x, acc[1][0]); acc[1][1] = fmaf(a1, hv.y, acc[1][1]);
      acc[1][2] = fmaf(a1, hv.z, acc[1][2]); acc[1][3] = fmaf(a1, hv.w, acc[1][3]);
      acc[2][0] = fmaf(a2, hv.x, acc[2][0]); acc[2][1] = fmaf(a2, hv.y, acc[2][1]);
      acc[2][2] = fmaf(a2, hv.z, acc[2][2]); acc[2][3] = fmaf(a2, hv.w, acc[2][3]);
      acc[3][0] = fmaf(a3, hv.x, acc[3][0]); acc[3][1] = fmaf(a3, hv.y, acc[3][1]);
      acc[3][2] = fmaf(a3, hv.z, acc[3][2]); acc[3][3] = fmaf(a3, hv.w, acc[3][3]);
    }
    float4 cwv;
    cwv.x = expf(sCW[cc * 64 + c4 * 4 + 0] - m) * cinv;
    cwv.y = expf(sCW[cc * 64 + c4 * 4 + 1] - m) * cinv;
    cwv.z = expf(sCW[cc * 64 + c4 * 4 + 2] - m) * cinv;
    cwv.w = expf(sCW[cc * 64 + c4 * 4 + 3] - m) * cinv;
    #pragma unroll
    for (int i = 0; i < 4; ++i) {
      float v0 = acc[i][0] * cwv.x;
      float v1 = acc[i][1] * cwv.y;
      float v2 = acc[i][2] * cwv.z;
      float v3 = acc[i][3] * cwv.w;
      zg[cc][i][0] = v0; zg[cc][i][1] = v1; zg[cc][i][2] = v2; zg[cc][i][3] = v3;
      rs[i]  += v0 + v1 + v2 + v3;
      rs2[i] += v0 * v0 + v1 * v1 + v2 * v2 + v3 * v3;
      u16x4 hh, ll;
      hh.x = f2bf(v0); ll.x = f2bf(v0 - bf2f(hh.x));
      hh.y = f2bf(v1); ll.y = f2bf(v1 - bf2f(hh.y));
      hh.z = f2bf(v2); ll.z = f2bf(v2 - bf2f(hh.z));
      hh.w = f2bf(v3); ll.w = f2bf(v3 - bf2f(hh.w));
      long o = obase + (long)(rb + i) * 192 + cc * 64 + c4 * 4;
      *(u16x4*)&ZgH[o] = hh;
      *(u16x4*)&ZgL[o] = ll;
    }
  }

  #pragma unroll
  for (int i = 0; i < 4; ++i) {
    float s = rs[i], s2 = rs2[i];
    s  += __shfl_xor(s, 1);  s  += __shfl_xor(s, 2);
    s  += __shfl_xor(s, 4);  s  += __shfl_xor(s, 8);
    s2 += __shfl_xor(s2, 1); s2 += __shfl_xor(s2, 2);
    s2 += __shfl_xor(s2, 4); s2 += __shfl_xor(s2, 8);
    rs[i] = s; rs2[i] = s2;
  }
  #pragma unroll
  for (int cc = 0; cc < 3; ++cc) {
    float4 g4 = *(const float4*)&ln_g[cc * 64 + c4 * 4];
    float4 b4 = *(const float4*)&ln_b[cc * 64 + c4 * 4];
    #pragma unroll
    for (int i = 0; i < 4; ++i) {
      float mu  = rs[i] * (1.f / 192.f);
      float var = rs2[i] * (1.f / 192.f) - mu * mu;
      float rstd = rsqrtf(var + 1e-5f);
      float v0 = (zg[cc][i][0] - mu) * rstd * g4.x + b4.x;
      float v1 = (zg[cc][i][1] - mu) * rstd * g4.y + b4.y;
      float v2 = (zg[cc][i][2] - mu) * rstd * g4.z + b4.z;
      float v3 = (zg[cc][i][3] - mu) * rstd * g4.w + b4.w;
      u16x4 hh, ll;
      hh.x = f2bf(v0); ll.x = f2bf(v0 - bf2f(hh.x));
      hh.y = f2bf(v1); ll.y = f2bf(v1 - bf2f(hh.y));
      hh.z = f2bf(v2); ll.z = f2bf(v2 - bf2f(hh.z));
      hh.w = f2bf(v3); ll.w = f2bf(v3 - bf2f(hh.w));
      long o = obase + (long)(rb + i) * 192 + cc * 64 + c4 * 4;
      *(u16x4*)&ZlnH[o] = hh;
      *(u16x4*)&ZlnL[o] = ll;
    }
  }
}

// ---------------- Zfused = Zfc + Zfm (f32, coalesced) ----------------
__global__ __launch_bounds__(256) void k_addout(
    const float* __restrict__ a, const float* __restrict__ b,
    float* __restrict__ out, long n)
{
  long i = ((long)blockIdx.x * 256 + threadIdx.x) * 4;
  if (i >= n) return;
  float4 va = *(const float4*)&a[i];
  float4 vb = *(const float4*)&b[i];
  float4 o;
  o.x = va.x + vb.x; o.y = va.y + vb.y; o.z = va.z + vb.z; o.w = va.w + vb.w;
  *(float4*)&out[i] = o;
}

// ---------------- output head finalize ----------------
__global__ __launch_bounds__(128) void k_final(
    const float* __restrict__ partial, const float* __restrict__ o1b,
    const float* __restrict__ o2w, const float* __restrict__ o2b,
    float* __restrict__ logits, int nsplit)
{
  int b = blockIdx.x, t = threadIdx.x;
  __shared__ float sH[128];
  float a = o1b[t];
  for (int s = 0; s < nsplit; ++s) a += partial[(long)s * 512 * 128 + b * 128 + t];
  a = fmaxf(a, 0.f);
  sH[t] = a;
  __syncthreads();
  if (t < 2) {
    float z = o2b[t];
    #pragma unroll 8
    for (int h = 0; h < 128; ++h) z = fmaf(sH[h], o2w[h * 2 + t], z);
    logits[b * 2 + t] = z;
  }
}

extern "C" void kernel_launch(void* const* d_in, const int* in_sizes, int n_in,
                              void* d_out, int out_size, void* d_ws, size_t ws_size,
                              hipStream_t stream)
{
  const float* x      = (const float*)d_in[0];
  const float* A_init = (const float*)d_in[1];
  const float* f1w = (const float*)d_in[2];
  const float* f1b = (const float*)d_in[3];
  const float* f2w = (const float*)d_in[4];
  const float* f2b = (const float*)d_in[5];
  const float* q1w = (const float*)d_in[6];
  const float* q1b = (const float*)d_in[7];
  const float* q2w = (const float*)d_in[8];
  const float* q2b = (const float*)d_in[9];
  const float* wqw = (const float*)d_in[10];
  const float* wqb = (const float*)d_in[11];
  const float* wkw = (const float*)d_in[12];
  const float* wkb = (const float*)d_in[13];
  const float* wvw = (const float*)d_in[14];
  const float* wvb = (const float*)d_in[15];
  const float* lng = (const float*)d_in[16];
  const float* lnb = (const float*)d_in[17];
  const float* fc1w = (const float*)d_in[18];
  const float* fc1b = (const float*)d_in[19];
  const float* fc2w = (const float*)d_in[20];
  const float* fc2b = (const float*)d_in[21];
  const float* fm1w = (const float*)d_in[22];
  const float* fm1b = (const float*)d_in[23];
  const float* fm2w = (const float*)d_in[24];
  const float* fm2b = (const float*)d_in[25];
  const float* o1w  = (const float*)d_in[26];
  const float* o1b  = (const float*)d_in[27];
  const float* o2w  = (const float*)d_in[28];
  const float* o2b  = (const float*)d_in[29];

  float* outF   = (float*)d_out;
  float* logits = outF;
  float* Zfused = outF + 1024;

  size_t off = 0;
  char* base = (char*)d_ws;
  auto alloc = [&](size_t bytes) -> void* {
    void* p = base + off;
    off += (bytes + 255) & ~(size_t)255;
    return p;
  };
  float* A_dyn  = (float*)alloc(3 * 4096 * 4);
  float* A_norm = (float*)alloc(3 * 4096 * 4);
  float* pmid   = (float*)alloc(3 * 32 * 256 * 4);
  float* mid    = (float*)alloc(3 * 256 * 4);
  u16* q1T_h  = (u16*)alloc((size_t)3 * 512 * 512 * 2);
  u16* q2T_h  = (u16*)alloc((size_t)3 * 512 * 512 * 2);
  u16* qkvT_h = (u16*)alloc((size_t)3 * 256 * 512 * 2);
  float* qkvb = (float*)alloc(3 * 256 * 4);
  u16* w1T = (u16*)alloc((size_t)2 * 256 * 192 * 2);
  u16* w2T = (u16*)alloc((size_t)2 * 256 * 192 * 2);
  float* fb1 = (float*)alloc(4 * 192 * 4);   // [fc1b|fm1b|fc2b|fm2b]
  float* Zl  = (float*)alloc(NZv * 4);
  u16* ZallH = (u16*)alloc((size_t)2 * NZv * 2);
  u16* ZallL = (u16*)alloc((size_t)2 * NZv * 2);
  u16* tmH   = (u16*)alloc((size_t)2 * NZv * 2);
  float* s2f = (float*)alloc((size_t)2 * NZv * 4);
  float* partial = (float*)alloc((size_t)24 * 512 * 128 * 4);

  u16* ZlnH = ZallH;        u16* ZlnL = ZallL;
  u16* ZgH  = ZallH + NZv;  u16* ZgL  = ZallL + NZv;

  // per-batch chunk: th, Gh, Gl, hh = 4 u16 arrays
  int NB = 512;
  while (NB > 32) {
    if (off + (size_t)NB * 786432ULL + 65536 <= ws_size) break;
    NB >>= 1;
  }
  long CM  = (long)NB * 64;
  long an  = (long)NB * 32768;
  u16* th = (u16*)alloc((size_t)3 * an * 2);   // t_a single bf16
  u16* Gh = (u16*)alloc((size_t)3 * an * 2);   // G hi
  u16* Gl = (u16*)alloc((size_t)3 * an * 2);   // G lo
  u16* hh = (u16*)alloc((size_t)3 * an * 2);   // h single bf16
  u16* qkvB = hh;                              // reuse h region after diffuse (bf16 qkv)

  // dynamic graph
  k_dg1<<<dim3(32, 3), 256, 0, stream>>>(A_init, f1w, pmid);
  k_dg2<<<dim3(3), 256, 0, stream>>>(pmid, f1b, mid);
  k_dg3<<<dim3(16, 3), 256, 0, stream>>>(mid, f2w, f2b, A_dyn, A_norm);
  // weight transposes
  k_cvt_wTh<<<dim3(16, 16, 3), 256, 0, stream>>>(q1w, q1T_h, 512, 512, 512);
  k_cvt_wTh<<<dim3(16, 16, 3), 256, 0, stream>>>(q2w, q2T_h, 512, 512, 512);
  k_cvt_qkvTh<<<dim3(16, 8, 3), 256, 0, stream>>>(wqw, wkw, wvw, qkvT_h);
  k_cvt_qkvb<<<dim3(3), 256, 0, stream>>>(wqb, wkb, wvb, qkvb);
  k_cvt_wTh<<<dim3(6, 8, 1), 256, 0, stream>>>(fc1w, w1T, 192, 192, 256);
  k_cvt_wTh<<<dim3(6, 8, 1), 256, 0, stream>>>(fm1w, w1T + 256 * 192, 192, 192, 256);
  k_cvt_wTh<<<dim3(6, 8, 1), 256, 0, stream>>>(fc2w, w2T, 192, 192, 256);
  k_cvt_wTh<<<dim3(6, 8, 1), 256, 0, stream>>>(fm2w, w2T + 256 * 192, 192, 192, 256);
  k_pack4<<<dim3(3), 256, 0, stream>>>(fc1b, fm1b, fc2b, fm2b, fb1);
  float* fb1p = fb1;
  float* fb2p = fb1 + 384;

  for (int b0 = 0; b0 < Bn; b0 += NB) {
    const float* xc = x + (long)b0 * 64 * 512;
    // t_a = elu(x@q1w + b) -> th (single bf16)  [A = f32 x, in-reg hi/lo split]
    k_mgemm<2, 2, 1, false><<<dim3(4, (unsigned)(NB / 2), 3), 256, 0, stream>>>(
        512, 512, 512, 512, 512,
        (const u16*)xc, nullptr, BCD * 2, q1T_h, (long)512 * 512,
        q1b, 512, nullptr, th, nullptr, an, nullptr);
    // h = t_a@q2w + b -> hh (single bf16)  [1-pass, depth-3 pipeline]
    k_mgemm<0, 2, 2, false><<<dim3(4, (unsigned)(NB / 2), 3), 256, 0, stream>>>(
        512, 512, 512, 512, 512,
        th, nullptr, an, q2T_h, (long)512 * 512,
        q2b, 512, nullptr, hh, nullptr, an, nullptr);
    // G = elu(A_norm@h + x) -> Gh/Gl (hi/lo — G precision is load-bearing, R13 lesson)
    k_diffuse<<<dim3(NB, 3), 256, 0, stream>>>(A_norm, hh, x, Gh, Gl, b0, NB);
    // QKV = G@Wqkv + b -> qkvB (bf16 single out, 2-pass A; dead-wave skip on pad)
    k_mgemm<0, 2, 0, false><<<dim3(2, (unsigned)(NB / 2), 3), 256, 0, stream>>>(
        256, 512, 512, 256, 192,
        Gh, Gl, an, qkvT_h, (long)256 * 512,
        qkvb, 256, nullptr, qkvB, nullptr, CM * 256, nullptr);
    k_attn<<<dim3(NB, 3), 256, 0, stream>>>(qkvB, A_dyn, Zl, b0, NB);
  }

  // fusion (cw computed in-block)
  k_fuse2<<<dim3(Bn), 256, 0, stream>>>(Zl, A_init, lng, lnb, ZgH, ZgL, ZlnH, ZlnL);
  // merged: t2 = relu(Zln@fc1+b) (z=0), t3 = elu(Zg@fm1+b) (z=1) -> [t2|t3] single bf16
  k_mgemm<3, 2, 0, false><<<dim3(2, 256, 2), 256, 0, stream>>>(
      256, 192, 192, 192, 192,
      ZallH, ZallL, NZv, w1T, (long)256 * 192,
      fb1p, 192, nullptr, tmH, nullptr, NZv, nullptr);
  // merged: Zfc = t2@fc2+b (z=0), Zfm = t3@fm2+b (z=1) -> [Zfc|Zfm] f32  [1-pass, depth-3]
  k_mgemm<0, 0, 2, false><<<dim3(2, 256, 2), 256, 0, stream>>>(
      256, 192, 192, 192, 192,
      tmH, nullptr, NZv, w2T, (long)256 * 192,
      fb2p, 192, s2f, nullptr, nullptr, NZv, nullptr);
  // Z_fused = Zfc + Zfm -> d_out
  k_addout<<<dim3((unsigned)(NZv / 1024)), 256, 0, stream>>>(s2f, s2f + NZv, Zfused, NZv);
  // output head (f32 split-K) + logits
  k_gemm<0, false, true><<<dim3(2, 8, 24), 256, 0, stream>>>(
      512, 128, 12288, Zfused, 0, 12288, o1w, 0, nullptr, 0,
      partial, (long)512 * 128, nullptr, 512);
  k_final<<<dim3(512), 128, 0, stream>>>(partial, o1b, o2w, o2b, logits, 24);
}

// Round 16
// 955.648 us; speedup vs baseline: 1.1019x; 1.1019x over previous
//
#include <hip/hip_runtime.h>
#include <math.h>

typedef unsigned short u16;
typedef __attribute__((ext_vector_type(8))) short short8;
typedef __attribute__((ext_vector_type(4))) float f32x4;
typedef __attribute__((ext_vector_type(4))) unsigned short u16x4;

// Problem dims
constexpr int  Bn   = 512;
constexpr int  Cch  = 64;
constexpr int  Dd   = 512;
constexpr int  DV3  = 192;
constexpr long BCD  = (long)Bn * Cch * Dd;
constexpr int  MTOT = Bn * Cch;                // 32768
constexpr long NZv  = (long)Bn * Cch * DV3;

__device__ __forceinline__ float eluf(float v) { return v > 0.f ? v : expm1f(v); }

__device__ __forceinline__ u16 f2bf(float f) {
  unsigned u = __float_as_uint(f);
  unsigned r = u + 0x7fffu + ((u >> 16) & 1u);
  return (u16)(r >> 16);
}
__device__ __forceinline__ float bf2f(u16 h) { return __uint_as_float(((unsigned)h) << 16); }

typedef __attribute__((address_space(1))) const unsigned int gu32;
typedef __attribute__((address_space(3))) unsigned int lu32;
__device__ __forceinline__ void g2l16(const void* g, void* l) {
  __builtin_amdgcn_global_load_lds((gu32*)g, (lu32*)l, 16, 0, 0);
}

// ---------------- dynamic graph (parallel, 3 stages) ----------------
__global__ __launch_bounds__(256) void k_dg1(
    const float* __restrict__ A_init, const float* __restrict__ f1w,
    float* __restrict__ pmid)
{
  int kb = blockIdx.x, z = blockIdx.y, t = threadIdx.x;
  __shared__ float sA[128];
  if (t < 128) sA[t] = A_init[kb * 128 + t];
  __syncthreads();
  const float* w1 = f1w + (long)z * 4096 * 256 + (long)kb * 128 * 256;
  float acc = 0.f;
  #pragma unroll 8
  for (int k = 0; k < 128; ++k) acc = fmaf(sA[k], w1[(long)k * 256 + t], acc);
  pmid[(z * 32 + kb) * 256 + t] = acc;
}

__global__ __launch_bounds__(256) void k_dg2(
    const float* __restrict__ pmid, const float* __restrict__ f1b,
    float* __restrict__ mid)
{
  int z = blockIdx.x, t = threadIdx.x;
  float s = f1b[z * 256 + t];
  #pragma unroll
  for (int kb = 0; kb < 32; ++kb) s += pmid[(z * 32 + kb) * 256 + t];
  mid[z * 256 + t] = eluf(s);
}

__global__ __launch_bounds__(256) void k_dg3(
    const float* __restrict__ mid, const float* __restrict__ f2w,
    const float* __restrict__ f2b,
    float* __restrict__ A_dyn, float* __restrict__ A_norm)
{
  int jb = blockIdx.x, z = blockIdx.y, t = threadIdx.x;
  __shared__ float sM[256];
  sM[t] = mid[z * 256 + t];
  __syncthreads();
  int j = jb * 256 + t;
  const float* w2 = f2w + (long)z * 256 * 4096;
  float acc = f2b[z * 4096 + j];
  #pragma unroll 8
  for (int k = 0; k < 256; ++k) acc = fmaf(sM[k], w2[(long)k * 4096 + j], acc);
  float a = fmaxf(acc, 0.f);
  A_dyn[z * 4096 + j] = a;
  float s = a;
  s += __shfl_xor(s, 1);  s += __shfl_xor(s, 2);  s += __shfl_xor(s, 4);
  s += __shfl_xor(s, 8);  s += __shfl_xor(s, 16); s += __shfl_xor(s, 32);
  A_norm[z * 4096 + j] = a / (s + 1e-6f);
}

// ---------------- weight transpose: (z,K,N) f32 -> (z,Npad,K) bf16 (hi only) ----------------
__global__ __launch_bounds__(256) void k_cvt_wTh(
    const float* __restrict__ w, u16* __restrict__ hT, int K, int N, int Npad)
{
  int k0 = blockIdx.x * 32, n0 = blockIdx.y * 32, z = blockIdx.z;
  int t = threadIdx.x;
  int tr = t >> 3, tc = (t & 7) * 4;
  long o = (long)z * Npad * K + (long)(n0 + tr) * K + k0 + tc;
  if (n0 >= N) {
    u16x4 zz = {0, 0, 0, 0};
    *(u16x4*)&hT[o] = zz;
    return;
  }
  __shared__ float sT[32][33];
  float4 v = *(const float4*)&w[(long)z * K * N + (long)(k0 + tr) * N + n0 + tc];
  sT[tr][tc + 0] = v.x; sT[tr][tc + 1] = v.y;
  sT[tr][tc + 2] = v.z; sT[tr][tc + 3] = v.w;
  __syncthreads();
  u16x4 h;
  h.x = f2bf(sT[tc + 0][tr]); h.y = f2bf(sT[tc + 1][tr]);
  h.z = f2bf(sT[tc + 2][tr]); h.w = f2bf(sT[tc + 3][tr]);
  *(u16x4*)&hT[o] = h;
}

// concat wq|wk|wv -> (z,256,512) transposed bf16, rows 192..255 zero
__global__ __launch_bounds__(256) void k_cvt_qkvTh(
    const float* __restrict__ wq, const float* __restrict__ wk, const float* __restrict__ wv,
    u16* __restrict__ hT)
{
  int k0 = blockIdx.x * 32, n0 = blockIdx.y * 32, z = blockIdx.z;
  int t = threadIdx.x;
  int tr = t >> 3, tc = (t & 7) * 4;
  long o = (long)z * 256 * 512 + (long)(n0 + tr) * 512 + k0 + tc;
  if (n0 >= 192) {
    u16x4 zz = {0, 0, 0, 0};
    *(u16x4*)&hT[o] = zz;
    return;
  }
  const float* src = (n0 < 64) ? wq : (n0 < 128) ? wk : wv;
  int nsub = n0 & 63;
  __shared__ float sT[32][33];
  float4 v = *(const float4*)&src[(long)z * 512 * 64 + (long)(k0 + tr) * 64 + nsub + tc];
  sT[tr][tc + 0] = v.x; sT[tr][tc + 1] = v.y;
  sT[tr][tc + 2] = v.z; sT[tr][tc + 3] = v.w;
  __syncthreads();
  u16x4 h;
  h.x = f2bf(sT[tc + 0][tr]); h.y = f2bf(sT[tc + 1][tr]);
  h.z = f2bf(sT[tc + 2][tr]); h.w = f2bf(sT[tc + 3][tr]);
  *(u16x4*)&hT[o] = h;
}

__global__ __launch_bounds__(256) void k_cvt_qkvb(
    const float* __restrict__ bq, const float* __restrict__ bk, const float* __restrict__ bv,
    float* __restrict__ bcat)
{
  int idx = blockIdx.x * 256 + threadIdx.x;
  if (idx >= 768) return;
  int z = idx >> 8, n = idx & 255;
  float v = 0.f;
  if (n < 64)       v = bq[z * 64 + n];
  else if (n < 128) v = bk[z * 64 + (n - 64)];
  else if (n < 192) v = bv[z * 64 + (n - 128)];
  bcat[idx] = v;
}

// pack 4 bias vectors (192 each) into contiguous buffer
__global__ __launch_bounds__(256) void k_pack4(
    const float* __restrict__ b0, const float* __restrict__ b1,
    const float* __restrict__ b2, const float* __restrict__ b3,
    float* __restrict__ dst)
{
  int idx = blockIdx.x * 256 + threadIdx.x;   // 768 total
  if (idx >= 768) return;
  int z = idx / 192, n = idx % 192;
  const float* s = (z == 0) ? b0 : (z == 1) ? b1 : (z == 2) ? b2 : b3;
  dst[idx] = s[n];
}

// ---------------- split GEMM, fat steps + counted vmcnt + setprio ----------------
// Tile 128x128, BK=32, 4 waves, double-buffered LDS, 2 K-tiles staged ahead,
// counted vmcnt (never 0 in main loop), raw s_barrier, setprio around MFMA.
// AMODE: 0 = A bf16 hi/lo (2-pass), 1 = A f32 (2-pass, in-reg extract),
//        2 = A bf16 single (1-pass).
// OMODE: 0 = f32 out, 1 = bf16 hi/lo out, 2 = bf16 hi-only out.
// ACT: 0 none, 1 relu, 2 elu, 3 per-z (z0 relu, z1 elu).
// [R14-exact config — measured best 955.8 us; R15's NBUF/live template variant
//  bloated VGPR 72->124 (occ 33->22%) and regressed; do not reintroduce.]
template<int ACT, int OMODE, int AMODE, bool RES>
__global__ __launch_bounds__(256) void k_mgemm(
    int N, int K, int lda, int ldo, int Nout,
    const u16* __restrict__ Ah, const u16* __restrict__ Al, long a_zs,
    const u16* __restrict__ Bh, long b_zs,
    const float* __restrict__ bias, long bias_zs,
    float* __restrict__ outF, u16* __restrict__ outH, u16* __restrict__ outL, long o_zs,
    const float* __restrict__ resid)
{
  // XCD-aware swizzle (all grids here have nwg % 8 == 0)
  int gx = gridDim.x, gy = gridDim.y;
  int nwg = gx * gy * (int)gridDim.z;
  int bid = (int)blockIdx.x + gx * ((int)blockIdx.y + gy * (int)blockIdx.z);
  int L = ((nwg & 7) == 0) ? ((bid & 7) * (nwg >> 3) + (bid >> 3)) : bid;
  int n0 = (L % gx) * 128;
  int m0 = ((L / gx) % gy) * 128;
  int z  = L / (gx * gy);

  const u16* ah = Ah + z * a_zs;
  const u16* al = (AMODE == 0) ? (Al + z * a_zs) : (const u16*)nullptr;
  const u16* bh = Bh + z * b_zs;

  constexpr int LDSU = (AMODE == 2) ? 8192 : 12288;
  constexpr int BOFF = (AMODE == 2) ? 4096 : 8192;
  __shared__ u16 sm[2][LDSU];

  int t = threadIdx.x, wv = t >> 6, ln = t & 63;
  int mh = wv >> 1, nh = wv & 1;
  int lr = ln & 15, lk8 = (ln >> 4) * 8;
  f32x4 acc[4][4] = {};

  auto stage = [&](int pp, int kt) {
    u16* smp = sm[pp];
    if (AMODE == 2) {
      #pragma unroll
      for (int s = 0; s < 4; ++s) {
        int c = s * 4 + wv;                  // 0..15
        if (c < 8) {
          const u16* g = ah + (long)(m0 + c * 16 + lr) * lda + kt + lk8;
          g2l16(g, smp + c * 512 + ln * 8);
        } else {
          int tile = c - 8;
          const u16* g = bh + (long)(n0 + tile * 16 + lr) * K + kt + lk8;
          g2l16(g, smp + 4096 + tile * 512 + ln * 8);
        }
      }
    } else {
      #pragma unroll
      for (int s = 0; s < 2; ++s) {
        int tile = s * 4 + wv;               // 0..7
        long rowA = (long)(m0 + tile * 16 + lr);
        if (AMODE == 1) {
          const float* Af = reinterpret_cast<const float*>(ah);
          const float* g = Af + rowA * lda + kt + lk8;
          g2l16(g,     smp + tile * 1024 + ln * 8);
          g2l16(g + 4, smp + tile * 1024 + 512 + ln * 8);
        } else {
          const u16* gA  = ah + rowA * lda + kt + lk8;
          const u16* gAl = al + rowA * lda + kt + lk8;
          g2l16(gA,  smp + tile * 512 + ln * 8);
          g2l16(gAl, smp + 4096 + tile * 512 + ln * 8);
        }
        const u16* gB = bh + (long)(n0 + tile * 16 + lr) * K + kt + lk8;
        g2l16(gB, smp + 8192 + tile * 512 + ln * 8);
      }
    }
  };

  int nsteps = K >> 5;
  stage(0, 0);
  stage(1, 32);

  for (int it = 0; it < nsteps; ++it) {
    int b = it & 1;
    if (it + 1 < nsteps) {
      if (AMODE == 2) { asm volatile("s_waitcnt vmcnt(4)" ::: "memory"); }
      else            { asm volatile("s_waitcnt vmcnt(6)" ::: "memory"); }
    } else {
      asm volatile("s_waitcnt vmcnt(0)" ::: "memory");
    }
    __builtin_amdgcn_sched_barrier(0);
    __builtin_amdgcn_s_barrier();

    short8 a_h[4], a_l[4], b_h[4];
    if (AMODE == 1) {
      const float* fp = reinterpret_cast<const float*>(sm[b]);
      #pragma unroll
      for (int f = 0; f < 4; ++f) {
        f32x4 lo = *(const f32x4*)&fp[(mh * 4 + f) * 512 + ln * 4];
        f32x4 hi = *(const f32x4*)&fp[(mh * 4 + f) * 512 + 256 + ln * 4];
        #pragma unroll
        for (int e = 0; e < 4; ++e) {
          unsigned ul = __float_as_uint(lo[e]), uh = __float_as_uint(hi[e]);
          a_h[f][e]     = (short)(ul >> 16);
          a_h[f][e + 4] = (short)(uh >> 16);
          float rl = lo[e] - __uint_as_float(ul & 0xffff0000u);
          float rh = hi[e] - __uint_as_float(uh & 0xffff0000u);
          a_l[f][e]     = (short)(__float_as_uint(rl) >> 16);
          a_l[f][e + 4] = (short)(__float_as_uint(rh) >> 16);
        }
      }
    } else {
      #pragma unroll
      for (int f = 0; f < 4; ++f) {
        a_h[f] = *(const short8*)&sm[b][(mh * 4 + f) * 512 + ln * 8];
        if (AMODE == 0)
          a_l[f] = *(const short8*)&sm[b][4096 + (mh * 4 + f) * 512 + ln * 8];
      }
    }
    #pragma unroll
    for (int f = 0; f < 4; ++f)
      b_h[f] = *(const short8*)&sm[b][BOFF + (nh * 4 + f) * 512 + ln * 8];

    asm volatile("s_waitcnt lgkmcnt(0)" ::: "memory");
    __builtin_amdgcn_sched_barrier(0);
    __builtin_amdgcn_s_barrier();          // all reads of buf b done

    if (it + 2 < nsteps) stage(b, (it + 2) << 5);

    __builtin_amdgcn_s_setprio(1);
    #pragma unroll
    for (int i = 0; i < 4; ++i)
      #pragma unroll
      for (int j = 0; j < 4; ++j) {
        acc[i][j] = __builtin_amdgcn_mfma_f32_16x16x32_bf16(a_h[i], b_h[j], acc[i][j], 0, 0, 0);
        if (AMODE != 2)
          acc[i][j] = __builtin_amdgcn_mfma_f32_16x16x32_bf16(a_l[i], b_h[j], acc[i][j], 0, 0, 0);
      }
    __builtin_amdgcn_s_setprio(0);
  }

  int colb = n0 + nh * 64, rowb = m0 + mh * 64;
  #pragma unroll
  for (int i = 0; i < 4; ++i) {
    #pragma unroll
    for (int j = 0; j < 4; ++j) {
      int col = colb + j * 16 + lr;
      if (col < Nout) {
        float bv = bias[z * bias_zs + col];
        #pragma unroll
        for (int r = 0; r < 4; ++r) {
          long row = rowb + i * 16 + (ln >> 4) * 4 + r;
          float v = acc[i][j][r] + bv;
          if (ACT == 1) v = fmaxf(v, 0.f);
          if (ACT == 2) v = eluf(v);
          if (ACT == 3) v = (z == 0) ? fmaxf(v, 0.f) : eluf(v);
          if (RES) v += resid[z * o_zs + row * ldo + col];
          if (OMODE == 0) {
            outF[z * o_zs + row * ldo + col] = v;
          } else if (OMODE == 1) {
            u16 h = f2bf(v);
            outH[z * o_zs + row * ldo + col] = h;
            outL[z * o_zs + row * ldo + col] = f2bf(v - bf2f(h));
          } else {
            outH[z * o_zs + row * ldo + col] = f2bf(v);
          }
        }
      }
    }
  }
}

// ---------------- diffusion: G = elu(A_norm @ h + x) -> bf16 hi/lo ----------------
__global__ __launch_bounds__(256) void k_diffuse(
    const float* __restrict__ A_norm, const u16* __restrict__ Hh,
    const float* __restrict__ x,
    u16* __restrict__ Gh, u16* __restrict__ Gl, int b0, int NB)
{
  int b = blockIdx.x, br = blockIdx.y, t = threadIdx.x;
  __shared__ float sAT[64 * 64];
  __shared__ float sH[64 * 64];
  const float* An = A_norm + br * 4096;
  for (int idx = t; idx < 4096; idx += 256)
    sAT[(idx & 63) * 64 + (idx >> 6)] = An[idx];
  const u16* hhb = Hh + ((long)br * NB + b) * (64 * 512);
  const float* xb = x + ((long)br * Bn + (b0 + b)) * (64 * 512);
  u16* Ghb = Gh + ((long)br * NB + b) * (64 * 512);
  u16* Glb = Gl + ((long)br * NB + b) * (64 * 512);
  int c4 = t & 15, rb = (t >> 4) * 4;
  for (int dc = 0; dc < 512; dc += 64) {
    __syncthreads();
    for (int idx = t * 4; idx < 4096; idx += 1024) {
      int r = idx >> 6, c = idx & 63;
      u16x4 ha = *(const u16x4*)&hhb[(long)r * 512 + dc + c];
      sH[idx + 0] = bf2f(ha.x);
      sH[idx + 1] = bf2f(ha.y);
      sH[idx + 2] = bf2f(ha.z);
      sH[idx + 3] = bf2f(ha.w);
    }
    __syncthreads();
    float acc[4][4] = {};
    #pragma unroll 4
    for (int j = 0; j < 64; ++j) {
      float a0 = sAT[j * 64 + rb + 0], a1 = sAT[j * 64 + rb + 1];
      float a2 = sAT[j * 64 + rb + 2], a3 = sAT[j * 64 + rb + 3];
      float4 hv = *(const float4*)&sH[j * 64 + c4 * 4];
      acc[0][0] = fmaf(a0, hv.x, acc[0][0]); acc[0][1] = fmaf(a0, hv.y, acc[0][1]);
      acc[0][2] = fmaf(a0, hv.z, acc[0][2]); acc[0][3] = fmaf(a0, hv.w, acc[0][3]);
      acc[1][0] = fmaf(a1, hv.x, acc[1][0]); acc[1][1] = fmaf(a1, hv.y, acc[1][1]);
      acc[1][2] = fmaf(a1, hv.z, acc[1][2]); acc[1][3] = fmaf(a1, hv.w, acc[1][3]);
      acc[2][0] = fmaf(a2, hv.x, acc[2][0]); acc[2][1] = fmaf(a2, hv.y, acc[2][1]);
      acc[2][2] = fmaf(a2, hv.z, acc[2][2]); acc[2][3] = fmaf(a2, hv.w, acc[2][3]);
      acc[3][0] = fmaf(a3, hv.x, acc[3][0]); acc[3][1] = fmaf(a3, hv.y, acc[3][1]);
      acc[3][2] = fmaf(a3, hv.z, acc[3][2]); acc[3][3] = fmaf(a3, hv.w, acc[3][3]);
    }
    #pragma unroll
    for (int i = 0; i < 4; ++i) {
      float4 xv = *(const float4*)&xb[(long)(rb + i) * 512 + dc + c4 * 4];
      float v0 = eluf(acc[i][0] + xv.x);
      float v1 = eluf(acc[i][1] + xv.y);
      float v2 = eluf(acc[i][2] + xv.z);
      float v3 = eluf(acc[i][3] + xv.w);
      u16x4 hh, ll;
      hh.x = f2bf(v0); ll.x = f2bf(v0 - bf2f(hh.x));
      hh.y = f2bf(v1); ll.y = f2bf(v1 - bf2f(hh.y));
      hh.z = f2bf(v2); ll.z = f2bf(v2 - bf2f(hh.z));
      hh.w = f2bf(v3); ll.w = f2bf(v3 - bf2f(hh.w));
      long o = (long)(rb + i) * 512 + dc + c4 * 4;
      *(u16x4*)&Ghb[o] = hh;
      *(u16x4*)&Glb[o] = ll;
    }
  }
}

// ---------------- attention + A_dyn apply (qkv in bf16) ----------------
__global__ __launch_bounds__(256) void k_attn(
    const u16* __restrict__ qkv, const float* __restrict__ A_dyn,
    float* __restrict__ Zl, int b0, int NB)
{
  int b = blockIdx.x, br = blockIdx.y, t = threadIdx.x;
  __shared__ float sQ[64 * 65];
  __shared__ float sK[64 * 65];
  __shared__ float sS[64 * 65];
  const u16* Qb = qkv + ((long)br * NB + b) * (64 * 256);
  for (int idx = t * 4; idx < 4096; idx += 1024) {
    int r = idx >> 6, c = idx & 63;
    u16x4 q4 = *(const u16x4*)&Qb[(long)r * 256 + c];
    u16x4 k4 = *(const u16x4*)&Qb[(long)r * 256 + 64 + c];
    sQ[r * 65 + c + 0] = bf2f(q4.x); sQ[r * 65 + c + 1] = bf2f(q4.y);
    sQ[r * 65 + c + 2] = bf2f(q4.z); sQ[r * 65 + c + 3] = bf2f(q4.w);
    sK[r * 65 + c + 0] = bf2f(k4.x); sK[r * 65 + c + 1] = bf2f(k4.y);
    sK[r * 65 + c + 2] = bf2f(k4.z); sK[r * 65 + c + 3] = bf2f(k4.w);
  }
  __syncthreads();
  int c4 = t & 15, rb = (t >> 4) * 4;
  float acc[4][4] = {};
  #pragma unroll 4
  for (int k = 0; k < 64; ++k) {
    float a0 = sQ[(rb + 0) * 65 + k], a1 = sQ[(rb + 1) * 65 + k];
    float a2 = sQ[(rb + 2) * 65 + k], a3 = sQ[(rb + 3) * 65 + k];
    #pragma unroll
    for (int q = 0; q < 4; ++q) {
      float bq = sK[(c4 * 4 + q) * 65 + k];
      acc[0][q] = fmaf(a0, bq, acc[0][q]); acc[1][q] = fmaf(a1, bq, acc[1][q]);
      acc[2][q] = fmaf(a2, bq, acc[2][q]); acc[3][q] = fmaf(a3, bq, acc[3][q]);
    }
  }
  #pragma unroll
  for (int i = 0; i < 4; ++i)
    #pragma unroll
    for (int q = 0; q < 4; ++q)
      sS[(rb + i) * 65 + c4 * 4 + q] = acc[i][q] * 0.125f;
  __syncthreads();
  {
    int r = t >> 2, l = t & 3;
    float m = -3.4e38f;
    #pragma unroll
    for (int c = 0; c < 16; ++c) m = fmaxf(m, sS[r * 65 + l * 16 + c]);
    m = fmaxf(m, __shfl_xor(m, 1));
    m = fmaxf(m, __shfl_xor(m, 2));
    float s = 0.f, e[16];
    #pragma unroll
    for (int c = 0; c < 16; ++c) { e[c] = expf(sS[r * 65 + l * 16 + c] - m); s += e[c]; }
    s += __shfl_xor(s, 1);
    s += __shfl_xor(s, 2);
    float inv = 1.f / s;
    #pragma unroll
    for (int c = 0; c < 16; ++c) sS[r * 65 + l * 16 + c] = e[c] * inv;
  }
  __syncthreads();
  for (int idx = t * 4; idx < 4096; idx += 1024) {
    int r = idx >> 6, c = idx & 63;
    u16x4 v4 = *(const u16x4*)&Qb[(long)r * 256 + 128 + c];
    sQ[r * 65 + c + 0] = bf2f(v4.x); sQ[r * 65 + c + 1] = bf2f(v4.y);
    sQ[r * 65 + c + 2] = bf2f(v4.z); sQ[r * 65 + c + 3] = bf2f(v4.w);
  }
  __syncthreads();
  float pv[4][4] = {};
  #pragma unroll 4
  for (int j = 0; j < 64; ++j) {
    float p0 = sS[(rb + 0) * 65 + j], p1 = sS[(rb + 1) * 65 + j];
    float p2 = sS[(rb + 2) * 65 + j], p3 = sS[(rb + 3) * 65 + j];
    #pragma unroll
    for (int q = 0; q < 4; ++q) {
      float vq = sQ[j * 65 + c4 * 4 + q];
      pv[0][q] = fmaf(p0, vq, pv[0][q]); pv[1][q] = fmaf(p1, vq, pv[1][q]);
      pv[2][q] = fmaf(p2, vq, pv[2][q]); pv[3][q] = fmaf(p3, vq, pv[3][q]);
    }
  }
  #pragma unroll
  for (int i = 0; i < 4; ++i)
    #pragma unroll
    for (int q = 0; q < 4; ++q)
      sK[(rb + i) * 65 + c4 * 4 + q] = pv[i][q];
  __syncthreads();
  const float* Ad = A_dyn + br * 4096;
  for (int idx = t; idx < 4096; idx += 256)
    sS[(idx >> 6) * 65 + (idx & 63)] = Ad[idx];
  __syncthreads();
  float zz[4][4] = {};
  #pragma unroll 4
  for (int j = 0; j < 64; ++j) {
    float a0 = sS[(rb + 0) * 65 + j], a1 = sS[(rb + 1) * 65 + j];
    float a2 = sS[(rb + 2) * 65 + j], a3 = sS[(rb + 3) * 65 + j];
    #pragma unroll
    for (int q = 0; q < 4; ++q) {
      float p = sK[j * 65 + c4 * 4 + q];
      zz[0][q] = fmaf(a0, p, zz[0][q]); zz[1][q] = fmaf(a1, p, zz[1][q]);
      zz[2][q] = fmaf(a2, p, zz[2][q]); zz[3][q] = fmaf(a3, p, zz[3][q]);
    }
  }
  long zbase = ((long)(b0 + b) * 64) * 192 + br * 64;
  #pragma unroll
  for (int i = 0; i < 4; ++i) {
    float4 o; o.x = zz[i][0]; o.y = zz[i][1]; o.z = zz[i][2]; o.w = zz[i][3];
    *(float4*)&Zl[zbase + (long)(rb + i) * 192 + c4 * 4] = o;
  }
}

// ---------------- f32 GEMM (output head only, split-K) ----------------
template<int ACT, bool RES, bool SPLITK>
__global__ __launch_bounds__(256) void k_gemm(
    int M, int N, int K,
    const float* __restrict__ A, long a_zs, int lda,
    const float* __restrict__ W, long w_zs,
    const float* __restrict__ bias, long b_zs,
    float* __restrict__ out, long o_zs,
    const float* __restrict__ resid, int k_chunk)
{
  int z  = blockIdx.z;
  int n0 = blockIdx.x * 64, m0 = blockIdx.y * 64;
  const float* Ab = A + (SPLITK ? 0 : z * a_zs);
  const float* Wb = W + (SPLITK ? 0 : z * w_zs);
  float* ob = out + z * o_zs;
  const float* bb = bias ? bias + z * b_zs : nullptr;
  const float* rb_ = RES ? resid + z * o_zs : nullptr;
  int k0   = SPLITK ? z * k_chunk : 0;
  int kend = SPLITK ? k0 + k_chunk : K;

  __shared__ float As[16][68];
  __shared__ float Bs[16][68];
  float acc[4][4] = {};
  int t  = threadIdx.x;
  int tm = t & 15, tn = t >> 4;
  int ar = t >> 2, ak = (t & 3) * 4;
  int bk = t >> 4, bn = (t & 15) * 4;

  for (int kt = k0; kt < kend; kt += 16) {
    float4 av = *(const float4*)&Ab[(long)(m0 + ar) * lda + kt + ak];
    float4 bv = *(const float4*)&Wb[(long)(kt + bk) * N + n0 + bn];
    __syncthreads();
    As[ak + 0][ar] = av.x; As[ak + 1][ar] = av.y;
    As[ak + 2][ar] = av.z; As[ak + 3][ar] = av.w;
    *(float4*)&Bs[bk][bn] = bv;
    __syncthreads();
    #pragma unroll
    for (int k = 0; k < 16; ++k) {
      float4 a = *(const float4*)&As[k][tm * 4];
      float4 b = *(const float4*)&Bs[k][tn * 4];
      acc[0][0] = fmaf(a.x, b.x, acc[0][0]); acc[0][1] = fmaf(a.x, b.y, acc[0][1]);
      acc[0][2] = fmaf(a.x, b.z, acc[0][2]); acc[0][3] = fmaf(a.x, b.w, acc[0][3]);
      acc[1][0] = fmaf(a.y, b.x, acc[1][0]); acc[1][1] = fmaf(a.y, b.y, acc[1][1]);
      acc[1][2] = fmaf(a.y, b.z, acc[1][2]); acc[1][3] = fmaf(a.y, b.w, acc[1][3]);
      acc[2][0] = fmaf(a.z, b.x, acc[2][0]); acc[2][1] = fmaf(a.z, b.y, acc[2][1]);
      acc[2][2] = fmaf(a.z, b.z, acc[2][2]); acc[2][3] = fmaf(a.z, b.w, acc[2][3]);
      acc[3][0] = fmaf(a.w, b.x, acc[3][0]); acc[3][1] = fmaf(a.w, b.y, acc[3][1]);
      acc[3][2] = fmaf(a.w, b.z, acc[3][2]); acc[3][3] = fmaf(a.w, b.w, acc[3][3]);
    }
  }

  #pragma unroll
  for (int i = 0; i < 4; ++i) {
    long row = m0 + tm * 4 + i;
    int  col = n0 + tn * 4;
    float v[4];
    #pragma unroll
    for (int j = 0; j < 4; ++j) {
      float x = acc[i][j] + (bb ? bb[col + j] : 0.f);
      if (ACT == 1) x = fmaxf(x, 0.f);
      if (ACT == 2) x = eluf(x);
      v[j] = x;
    }
    if (RES) {
      float4 r = *(const float4*)&rb_[row * N + col];
      v[0] += r.x; v[1] += r.y; v[2] += r.z; v[3] += r.w;
    }
    float4 o; o.x = v[0]; o.y = v[1]; o.z = v[2]; o.w = v[3];
    *(float4*)&ob[row * N + col] = o;
  }
}

// ---------------- fusion: cw softmax + Zg = (A_init @ Zl) * cw; Zln = LN(Zg) ----------------
__global__ __launch_bounds__(256) void k_fuse2(
    const float* __restrict__ Zl, const float* __restrict__ A_init,
    const float* __restrict__ ln_g, const float* __restrict__ ln_b,
    u16* __restrict__ ZgH, u16* __restrict__ ZgL,
    u16* __restrict__ ZlnH, u16* __restrict__ ZlnL)
{
  int b = blockIdx.x, t = threadIdx.x;
  __shared__ float sAT[64 * 64];
  __shared__ float sH[64 * 68];
  __shared__ float sCW[192];
  const float* Zb = Zl + (long)b * 12288;
  if (t < 192) {
    float s = 0.f;
    #pragma unroll 8
    for (int j = 0; j < 64; ++j) s += Zb[j * 192 + t];
    sCW[t] = s * (1.f / 64.f);
  }
  for (int idx = t; idx < 4096; idx += 256)
    sAT[(idx & 63) * 64 + (idx >> 6)] = A_init[idx];
  __syncthreads();
  float m = -3.4e38f;
  for (int d = 0; d < 192; ++d) m = fmaxf(m, sCW[d]);
  float ssum = 0.f;
  for (int d = 0; d < 192; ++d) ssum += expf(sCW[d] - m);
  float cinv = 1.f / ssum;

  long obase = (long)b * 12288;
  int c4 = t & 15, rb = (t >> 4) * 4;
  float zg[3][4][4];
  float rs[4] = {0.f, 0.f, 0.f, 0.f};
  float rs2[4] = {0.f, 0.f, 0.f, 0.f};

  #pragma unroll
  for (int cc = 0; cc < 3; ++cc) {
    __syncthreads();
    for (int idx = t * 4; idx < 4096; idx += 1024) {
      int r = idx >> 6, c = idx & 63;
      float4 v = *(const float4*)&Zb[(long)r * 192 + cc * 64 + c];
      *(float4*)&sH[r * 68 + c] = v;
    }
    __syncthreads();
    float acc[4][4] = {};
    #pragma unroll 4
    for (int j = 0; j < 64; ++j) {
      float a0 = sAT[j * 64 + rb + 0], a1 = sAT[j * 64 + rb + 1];
      float a2 = sAT[j * 64 + rb + 2], a3 = sAT[j * 64 + rb + 3];
      float4 hv = *(const float4*)&sH[j * 68 + c4 * 4];
      acc[0][0] = fmaf(a0, hv.x, acc[0][0]); acc[0][1] = fmaf(a0, hv.y, acc[0][1]);
      acc[0][2] = fmaf(a0, hv.z, acc[0][2]); acc[0][3] = fmaf(a0, hv.w, acc[0][3]);
      acc[1][0] = fmaf(a1, hv.x, acc[1][0]); acc[1][1] = fmaf(a1, hv.y, acc[1][1]);
      acc[1][2] = fmaf(a1, hv.z, acc[1][2]); acc[1][3] = fmaf(a1, hv.w, acc[1][3]);
      acc[2][0] = fmaf(a2, hv.x, acc[2][0]); acc[2][1] = fmaf(a2, hv.y, acc[2][1]);
      acc[2][2] = fmaf(a2, hv.z, acc[2][2]); acc[2][3] = fmaf(a2, hv.w, acc[2][3]);
      acc[3][0] = fmaf(a3, hv.x, acc[3][0]); acc[3][1] = fmaf(a3, hv.y, acc[3][1]);
      acc[3][2] = fmaf(a3, hv.z, acc[3][2]); acc[3][3] = fmaf(a3, hv.w, acc[3][3]);
    }
    float4 cwv;
    cwv.x = expf(sCW[cc * 64 + c4 * 4 + 0] - m) * cinv;
    cwv.y = expf(sCW[cc * 64 + c4 * 4 + 1] - m) * cinv;
    cwv.z = expf(sCW[cc * 64 + c4 * 4 + 2] - m) * cinv;
    cwv.w = expf(sCW[cc * 64 + c4 * 4 + 3] - m) * cinv;
    #pragma unroll
    for (int i = 0; i < 4; ++i) {
      float v0 = acc[i][0] * cwv.x;
      float v1 = acc[i][1] * cwv.y;
      float v2 = acc[i][2] * cwv.z;
      float v3 = acc[i][3] * cwv.w;
      zg[cc][i][0] = v0; zg[cc][i][1] = v1; zg[cc][i][2] = v2; zg[cc][i][3] = v3;
      rs[i]  += v0 + v1 + v2 + v3;
      rs2[i] += v0 * v0 + v1 * v1 + v2 * v2 + v3 * v3;
      u16x4 hh, ll;
      hh.x = f2bf(v0); ll.x = f2bf(v0 - bf2f(hh.x));
      hh.y = f2bf(v1); ll.y = f2bf(v1 - bf2f(hh.y));
      hh.z = f2bf(v2); ll.z = f2bf(v2 - bf2f(hh.z));
      hh.w = f2bf(v3); ll.w = f2bf(v3 - bf2f(hh.w));
      long o = obase + (long)(rb + i) * 192 + cc * 64 + c4 * 4;
      *(u16x4*)&ZgH[o] = hh;
      *(u16x4*)&ZgL[o] = ll;
    }
  }

  #pragma unroll
  for (int i = 0; i < 4; ++i) {
    float s = rs[i], s2 = rs2[i];
    s  += __shfl_xor(s, 1);  s  += __shfl_xor(s, 2);
    s  += __shfl_xor(s, 4);  s  += __shfl_xor(s, 8);
    s2 += __shfl_xor(s2, 1); s2 += __shfl_xor(s2, 2);
    s2 += __shfl_xor(s2, 4); s2 += __shfl_xor(s2, 8);
    rs[i] = s; rs2[i] = s2;
  }
  #pragma unroll
  for (int cc = 0; cc < 3; ++cc) {
    float4 g4 = *(const float4*)&ln_g[cc * 64 + c4 * 4];
    float4 b4 = *(const float4*)&ln_b[cc * 64 + c4 * 4];
    #pragma unroll
    for (int i = 0; i < 4; ++i) {
      float mu  = rs[i] * (1.f / 192.f);
      float var = rs2[i] * (1.f / 192.f) - mu * mu;
      float rstd = rsqrtf(var + 1e-5f);
      float v0 = (zg[cc][i][0] - mu) * rstd * g4.x + b4.x;
      float v1 = (zg[cc][i][1] - mu) * rstd * g4.y + b4.y;
      float v2 = (zg[cc][i][2] - mu) * rstd * g4.z + b4.z;
      float v3 = (zg[cc][i][3] - mu) * rstd * g4.w + b4.w;
      u16x4 hh, ll;
      hh.x = f2bf(v0); ll.x = f2bf(v0 - bf2f(hh.x));
      hh.y = f2bf(v1); ll.y = f2bf(v1 - bf2f(hh.y));
      hh.z = f2bf(v2); ll.z = f2bf(v2 - bf2f(hh.z));
      hh.w = f2bf(v3); ll.w = f2bf(v3 - bf2f(hh.w));
      long o = obase + (long)(rb + i) * 192 + cc * 64 + c4 * 4;
      *(u16x4*)&ZlnH[o] = hh;
      *(u16x4*)&ZlnL[o] = ll;
    }
  }
}

// ---------------- Zfused = Zfc + Zfm (f32, coalesced) ----------------
__global__ __launch_bounds__(256) void k_addout(
    const float* __restrict__ a, const float* __restrict__ b,
    float* __restrict__ out, long n)
{
  long i = ((long)blockIdx.x * 256 + threadIdx.x) * 4;
  if (i >= n) return;
  float4 va = *(const float4*)&a[i];
  float4 vb = *(const float4*)&b[i];
  float4 o;
  o.x = va.x + vb.x; o.y = va.y + vb.y; o.z = va.z + vb.z; o.w = va.w + vb.w;
  *(float4*)&out[i] = o;
}

// ---------------- output head finalize ----------------
__global__ __launch_bounds__(128) void k_final(
    const float* __restrict__ partial, const float* __restrict__ o1b,
    const float* __restrict__ o2w, const float* __restrict__ o2b,
    float* __restrict__ logits, int nsplit)
{
  int b = blockIdx.x, t = threadIdx.x;
  __shared__ float sH[128];
  float a = o1b[t];
  for (int s = 0; s < nsplit; ++s) a += partial[(long)s * 512 * 128 + b * 128 + t];
  a = fmaxf(a, 0.f);
  sH[t] = a;
  __syncthreads();
  if (t < 2) {
    float z = o2b[t];
    #pragma unroll 8
    for (int h = 0; h < 128; ++h) z = fmaf(sH[h], o2w[h * 2 + t], z);
    logits[b * 2 + t] = z;
  }
}

extern "C" void kernel_launch(void* const* d_in, const int* in_sizes, int n_in,
                              void* d_out, int out_size, void* d_ws, size_t ws_size,
                              hipStream_t stream)
{
  const float* x      = (const float*)d_in[0];
  const float* A_init = (const float*)d_in[1];
  const float* f1w = (const float*)d_in[2];
  const float* f1b = (const float*)d_in[3];
  const float* f2w = (const float*)d_in[4];
  const float* f2b = (const float*)d_in[5];
  const float* q1w = (const float*)d_in[6];
  const float* q1b = (const float*)d_in[7];
  const float* q2w = (const float*)d_in[8];
  const float* q2b = (const float*)d_in[9];
  const float* wqw = (const float*)d_in[10];
  const float* wqb = (const float*)d_in[11];
  const float* wkw = (const float*)d_in[12];
  const float* wkb = (const float*)d_in[13];
  const float* wvw = (const float*)d_in[14];
  const float* wvb = (const float*)d_in[15];
  const float* lng = (const float*)d_in[16];
  const float* lnb = (const float*)d_in[17];
  const float* fc1w = (const float*)d_in[18];
  const float* fc1b = (const float*)d_in[19];
  const float* fc2w = (const float*)d_in[20];
  const float* fc2b = (const float*)d_in[21];
  const float* fm1w = (const float*)d_in[22];
  const float* fm1b = (const float*)d_in[23];
  const float* fm2w = (const float*)d_in[24];
  const float* fm2b = (const float*)d_in[25];
  const float* o1w  = (const float*)d_in[26];
  const float* o1b  = (const float*)d_in[27];
  const float* o2w  = (const float*)d_in[28];
  const float* o2b  = (const float*)d_in[29];

  float* outF   = (float*)d_out;
  float* logits = outF;
  float* Zfused = outF + 1024;

  size_t off = 0;
  char* base = (char*)d_ws;
  auto alloc = [&](size_t bytes) -> void* {
    void* p = base + off;
    off += (bytes + 255) & ~(size_t)255;
    return p;
  };
  float* A_dyn  = (float*)alloc(3 * 4096 * 4);
  float* A_norm = (float*)alloc(3 * 4096 * 4);
  float* pmid   = (float*)alloc(3 * 32 * 256 * 4);
  float* mid    = (float*)alloc(3 * 256 * 4);
  u16* q1T_h  = (u16*)alloc((size_t)3 * 512 * 512 * 2);
  u16* q2T_h  = (u16*)alloc((size_t)3 * 512 * 512 * 2);
  u16* qkvT_h = (u16*)alloc((size_t)3 * 256 * 512 * 2);
  float* qkvb = (float*)alloc(3 * 256 * 4);
  u16* w1T = (u16*)alloc((size_t)2 * 256 * 192 * 2);
  u16* w2T = (u16*)alloc((size_t)2 * 256 * 192 * 2);
  float* fb1 = (float*)alloc(4 * 192 * 4);   // [fc1b|fm1b|fc2b|fm2b]
  float* Zl  = (float*)alloc(NZv * 4);
  u16* ZallH = (u16*)alloc((size_t)2 * NZv * 2);
  u16* ZallL = (u16*)alloc((size_t)2 * NZv * 2);
  u16* tmH   = (u16*)alloc((size_t)2 * NZv * 2);
  float* s2f = (float*)alloc((size_t)2 * NZv * 4);
  float* partial = (float*)alloc((size_t)24 * 512 * 128 * 4);

  u16* ZlnH = ZallH;        u16* ZlnL = ZallL;
  u16* ZgH  = ZallH + NZv;  u16* ZgL  = ZallL + NZv;

  // per-batch chunk: th, Gh, Gl, hh = 4 u16 arrays
  int NB = 512;
  while (NB > 32) {
    if (off + (size_t)NB * 786432ULL + 65536 <= ws_size) break;
    NB >>= 1;
  }
  long CM  = (long)NB * 64;
  long an  = (long)NB * 32768;
  u16* th = (u16*)alloc((size_t)3 * an * 2);   // t_a single bf16
  u16* Gh = (u16*)alloc((size_t)3 * an * 2);   // G hi
  u16* Gl = (u16*)alloc((size_t)3 * an * 2);   // G lo
  u16* hh = (u16*)alloc((size_t)3 * an * 2);   // h single bf16
  u16* qkvB = hh;                              // reuse h region after diffuse (bf16 qkv)

  // dynamic graph
  k_dg1<<<dim3(32, 3), 256, 0, stream>>>(A_init, f1w, pmid);
  k_dg2<<<dim3(3), 256, 0, stream>>>(pmid, f1b, mid);
  k_dg3<<<dim3(16, 3), 256, 0, stream>>>(mid, f2w, f2b, A_dyn, A_norm);
  // weight transposes
  k_cvt_wTh<<<dim3(16, 16, 3), 256, 0, stream>>>(q1w, q1T_h, 512, 512, 512);
  k_cvt_wTh<<<dim3(16, 16, 3), 256, 0, stream>>>(q2w, q2T_h, 512, 512, 512);
  k_cvt_qkvTh<<<dim3(16, 8, 3), 256, 0, stream>>>(wqw, wkw, wvw, qkvT_h);
  k_cvt_qkvb<<<dim3(3), 256, 0, stream>>>(wqb, wkb, wvb, qkvb);
  k_cvt_wTh<<<dim3(6, 8, 1), 256, 0, stream>>>(fc1w, w1T, 192, 192, 256);
  k_cvt_wTh<<<dim3(6, 8, 1), 256, 0, stream>>>(fm1w, w1T + 256 * 192, 192, 192, 256);
  k_cvt_wTh<<<dim3(6, 8, 1), 256, 0, stream>>>(fc2w, w2T, 192, 192, 256);
  k_cvt_wTh<<<dim3(6, 8, 1), 256, 0, stream>>>(fm2w, w2T + 256 * 192, 192, 192, 256);
  k_pack4<<<dim3(3), 256, 0, stream>>>(fc1b, fm1b, fc2b, fm2b, fb1);
  float* fb1p = fb1;
  float* fb2p = fb1 + 384;

  for (int b0 = 0; b0 < Bn; b0 += NB) {
    const float* xc = x + (long)b0 * 64 * 512;
    // t_a = elu(x@q1w + b) -> th (single bf16)  [A = f32 x, in-reg hi/lo split]
    k_mgemm<2, 2, 1, false><<<dim3(4, (unsigned)(NB / 2), 3), 256, 0, stream>>>(
        512, 512, 512, 512, 512,
        (const u16*)xc, nullptr, BCD * 2, q1T_h, (long)512 * 512,
        q1b, 512, nullptr, th, nullptr, an, nullptr);
    // h = t_a@q2w + b -> hh (single bf16)  [1-pass]
    k_mgemm<0, 2, 2, false><<<dim3(4, (unsigned)(NB / 2), 3), 256, 0, stream>>>(
        512, 512, 512, 512, 512,
        th, nullptr, an, q2T_h, (long)512 * 512,
        q2b, 512, nullptr, hh, nullptr, an, nullptr);
    // G = elu(A_norm@h + x) -> Gh/Gl (hi/lo — G precision is load-bearing, R13 lesson)
    k_diffuse<<<dim3(NB, 3), 256, 0, stream>>>(A_norm, hh, x, Gh, Gl, b0, NB);
    // QKV = G@Wqkv + b -> qkvB (bf16 single out, 2-pass A; reuses h region)
    k_mgemm<0, 2, 0, false><<<dim3(2, (unsigned)(NB / 2), 3), 256, 0, stream>>>(
        256, 512, 512, 256, 192,
        Gh, Gl, an, qkvT_h, (long)256 * 512,
        qkvb, 256, nullptr, qkvB, nullptr, CM * 256, nullptr);
    k_attn<<<dim3(NB, 3), 256, 0, stream>>>(qkvB, A_dyn, Zl, b0, NB);
  }

  // fusion (cw computed in-block)
  k_fuse2<<<dim3(Bn), 256, 0, stream>>>(Zl, A_init, lng, lnb, ZgH, ZgL, ZlnH, ZlnL);
  // merged: t2 = relu(Zln@fc1+b) (z=0), t3 = elu(Zg@fm1+b) (z=1) -> [t2|t3] single bf16
  k_mgemm<3, 2, 0, false><<<dim3(2, 256, 2), 256, 0, stream>>>(
      256, 192, 192, 192, 192,
      ZallH, ZallL, NZv, w1T, (long)256 * 192,
      fb1p, 192, nullptr, tmH, nullptr, NZv, nullptr);
  // merged: Zfc = t2@fc2+b (z=0), Zfm = t3@fm2+b (z=1) -> [Zfc|Zfm] f32  [1-pass]
  k_mgemm<0, 0, 2, false><<<dim3(2, 256, 2), 256, 0, stream>>>(
      256, 192, 192, 192, 192,
      tmH, nullptr, NZv, w2T, (long)256 * 192,
      fb2p, 192, s2f, nullptr, nullptr, NZv, nullptr);
  // Z_fused = Zfc + Zfm -> d_out
  k_addout<<<dim3((unsigned)(NZv / 1024)), 256, 0, stream>>>(s2f, s2f + NZv, Zfused, NZv);
  // output head (f32 split-K) + logits
  k_gemm<0, false, true><<<dim3(2, 8, 24), 256, 0, stream>>>(
      512, 128, 12288, Zfused, 0, 12288, o1w, 0, nullptr, 0,
      partial, (long)512 * 128, nullptr, 512);
  k_final<<<dim3(512), 128, 0, stream>>>(partial, o1b, o2w, o2b, logits, 24);
}